// Round 3
// baseline (1249.296 us; speedup 1.0000x reference)
//
#include <hip/hip_runtime.h>

typedef unsigned int u32;
typedef unsigned short u16;

typedef _Float16 f16x8 __attribute__((ext_vector_type(8)));
typedef float    f32x4 __attribute__((ext_vector_type(4)));

constexpr int NN = 100000;   // nodes
constexpr int NE = 1600000;  // edges
constexpr int NG = 256;      // graphs
constexpr int DH = 128;      // hidden dim
constexpr int NL = 4;        // GIN layers
constexpr int NT = NN / 16;  // 6250 16-row tiles

// d_out layout (fp32 elements)
constexpr long long OFF_EMB  = 0;                       // 5*NN*128
constexpr long long OFF_PS   = 64000000LL;              // 256*128
constexpr long long OFF_L1   = OFF_PS  + (long long)NG*DH;
constexpr long long OFF_L1D  = OFF_L1  + (long long)NG*DH;
constexpr long long OFF_L2   = OFF_L1D + (long long)NG*DH;
constexpr long long OFF_SOFT = OFF_L2  + (long long)NG*8;

__device__ __forceinline__ u16 f2h(float f) {
    union { _Float16 h; u16 s; } c; c.h = (_Float16)f; return c.s;
}
__device__ __forceinline__ float h2f(u16 s) {
    union { u16 s; _Float16 h; } c; c.s = s; return (float)c.h;
}

union U16x8 { uint4 u; f16x8 h; u16 s[8]; };

// ---------------- CSR build ----------------
__global__ __launch_bounds__(256) void k_hist(const int* __restrict__ ei, int* __restrict__ cnt) {
    int e = blockIdx.x * 256 + threadIdx.x;
    if (e < NE) atomicAdd(&cnt[ei[e]], 1);
}

__global__ __launch_bounds__(256) void k_scan1(const int* __restrict__ cnt,
                                               int* __restrict__ rp, int* __restrict__ bsum) {
    __shared__ int sd[256];
    int t = threadIdx.x;
    int base = blockIdx.x * 1024 + t * 4;
    int v0 = (base + 0 < NN) ? cnt[base + 0] : 0;
    int v1 = (base + 1 < NN) ? cnt[base + 1] : 0;
    int v2 = (base + 2 < NN) ? cnt[base + 2] : 0;
    int v3 = (base + 3 < NN) ? cnt[base + 3] : 0;
    int s = v0 + v1 + v2 + v3;
    sd[t] = s; __syncthreads();
    for (int off = 1; off < 256; off <<= 1) {
        int x = (t >= off) ? sd[t - off] : 0;
        __syncthreads();
        sd[t] += x;
        __syncthreads();
    }
    int e = sd[t] - s;
    if (base + 0 < NN) rp[base + 0] = e; e += v0;
    if (base + 1 < NN) rp[base + 1] = e; e += v1;
    if (base + 2 < NN) rp[base + 2] = e; e += v2;
    if (base + 3 < NN) rp[base + 3] = e;
    if (t == 255) bsum[blockIdx.x] = sd[255];
}

__global__ void k_scan2(int* __restrict__ bsum, int nb) {
    __shared__ int sd[128];
    int t = threadIdx.x;
    int v = (t < nb) ? bsum[t] : 0;
    sd[t] = v; __syncthreads();
    for (int off = 1; off < 128; off <<= 1) {
        int x = (t >= off) ? sd[t - off] : 0;
        __syncthreads();
        sd[t] += x;
        __syncthreads();
    }
    if (t < nb) bsum[t] = sd[t] - v;
}

__global__ __launch_bounds__(256) void k_scan3(int* __restrict__ rp, const int* __restrict__ bsum) {
    int t = threadIdx.x;
    int base = blockIdx.x * 1024 + t * 4;
    int add = bsum[blockIdx.x];
    #pragma unroll
    for (int j = 0; j < 4; ++j)
        if (base + j < NN) rp[base + j] += add;
    if (blockIdx.x == 0 && t == 0) rp[NN] = NE;
}

__global__ __launch_bounds__(256) void k_scatter(const int* __restrict__ ei,
                                                 const float* __restrict__ mask,
                                                 const int* __restrict__ rp,
                                                 int* __restrict__ cur,
                                                 int2* __restrict__ pairs) {
    int e = blockIdx.x * 256 + threadIdx.x;
    if (e >= NE) return;
    int d = ei[e];
    int pos = rp[d] + atomicAdd(&cur[d], 1);
    pairs[pos] = make_int2(ei[NE + e], __float_as_int(mask[e]));
}

// ---------------- first GEMM: h0 = x @ W_first^T + b (fp32 A, fp16 MFMA hi/lo W) ----
__global__ __launch_bounds__(256) void k_gemm0(const float* __restrict__ A,
                                               const float* __restrict__ W,
                                               const float* __restrict__ bias,
                                               u16* __restrict__ outh,
                                               float* __restrict__ outf) {
    __shared__ float stage[4][16 * 36];
    float* st = stage[threadIdx.x >> 6];
    const int lane = threadIdx.x & 63;
    const int wid = (blockIdx.x * 256 + threadIdx.x) >> 6;
    const int nwaves = (gridDim.x * 256) >> 6;
    const int m = lane & 15, q = lane >> 4;
    const int pair = wid & 3;
    const int tile0 = wid >> 2;
    const int tstride = nwaves >> 2;

    f16x8 bhi[2][4], blo[2][4];
    float bs[2];
    #pragma unroll
    for (int t = 0; t < 2; ++t) {
        int n = pair * 32 + t * 16 + m;
        const float* wr = W + (size_t)n * 128 + q * 8;
        bs[t] = bias[n];
        #pragma unroll
        for (int kb = 0; kb < 4; ++kb) {
            float4 f0 = *(const float4*)(wr + kb * 32);
            float4 f1 = *(const float4*)(wr + kb * 32 + 4);
            float f[8] = {f0.x, f0.y, f0.z, f0.w, f1.x, f1.y, f1.z, f1.w};
            f16x8 hi, lo;
            #pragma unroll
            for (int j = 0; j < 8; ++j) {
                _Float16 h = (_Float16)f[j];
                hi[j] = h;
                lo[j] = (_Float16)(f[j] - (float)h);
            }
            bhi[t][kb] = hi;
            blo[t][kb] = lo;
        }
    }

    const int rdrow = lane >> 2, rdcg = lane & 3;
    for (int tile = tile0; tile < NT; tile += tstride) {
        int row0 = tile * 16;
        const float* ap = A + (size_t)(row0 + m) * 128 + q * 8;
        f16x8 af[4];
        #pragma unroll
        for (int kb = 0; kb < 4; ++kb) {
            float4 f0 = *(const float4*)(ap + kb * 32);
            float4 f1 = *(const float4*)(ap + kb * 32 + 4);
            f16x8 h;
            h[0] = (_Float16)f0.x; h[1] = (_Float16)f0.y;
            h[2] = (_Float16)f0.z; h[3] = (_Float16)f0.w;
            h[4] = (_Float16)f1.x; h[5] = (_Float16)f1.y;
            h[6] = (_Float16)f1.z; h[7] = (_Float16)f1.w;
            af[kb] = h;
        }
        f32x4 acc[2] = {{0.f,0.f,0.f,0.f},{0.f,0.f,0.f,0.f}};
        #pragma unroll
        for (int t = 0; t < 2; ++t)
            #pragma unroll
            for (int kb = 0; kb < 4; ++kb) {
                acc[t] = __builtin_amdgcn_mfma_f32_16x16x32_f16(af[kb], bhi[t][kb], acc[t], 0, 0, 0);
                acc[t] = __builtin_amdgcn_mfma_f32_16x16x32_f16(af[kb], blo[t][kb], acc[t], 0, 0, 0);
            }
        #pragma unroll
        for (int t = 0; t < 2; ++t)
            #pragma unroll
            for (int r = 0; r < 4; ++r)
                st[(q * 4 + r) * 36 + t * 16 + m] = acc[t][r] + bs[t];
        float4 v0 = *(const float4*)&st[rdrow * 36 + rdcg * 8];
        float4 v1 = *(const float4*)&st[rdrow * 36 + rdcg * 8 + 4];
        size_t gbase = (size_t)(row0 + rdrow) * 128 + pair * 32 + rdcg * 8;
        U16x8 p;
        p.s[0] = f2h(v0.x); p.s[1] = f2h(v0.y); p.s[2] = f2h(v0.z); p.s[3] = f2h(v0.w);
        p.s[4] = f2h(v1.x); p.s[5] = f2h(v1.y); p.s[6] = f2h(v1.z); p.s[7] = f2h(v1.w);
        *(uint4*)(outh + gbase) = p.u;
        *(float4*)(outf + gbase) = v0;
        *(float4*)(outf + gbase + 4) = v1;
    }
}

// ---------------- fused GIN layer: agg + SLP0 + SLP1 ----------------
// Block = 4 waves, 16-node tile, grid-stride. Wave w owns cols [w*32,w*32+32)
// of BOTH SLPs (hi/lo W frags in VGPRs, ~190 VGPR total -> 2 waves/SIMD).
__global__ __launch_bounds__(256, 2) void k_layer(
        const u16* __restrict__ hin,
        const int2* __restrict__ pairs,
        const int* __restrict__ rp,
        const float* __restrict__ eps, int layer,
        const float* __restrict__ W0, const float* __restrict__ b0v,
        const float* __restrict__ W1, const float* __restrict__ b1v,
        u16* __restrict__ outh, float* __restrict__ outf) {
    __shared__ u16 tA[16 * 136];       // agg tile, row stride 136 halves
    __shared__ u16 tB[16 * 136];       // SLP0 output tile
    __shared__ float stg[4][16 * 36];  // epilogue stage (wave-private)

    const int tid = threadIdx.x;
    const int w = tid >> 6;
    const int lane = tid & 63;
    const int m = lane & 15, q = lane >> 4;
    float* st = stg[w];

    // W fragments, both layers: B[k][n]=W[n][k]; lane holds n=m, k=q*8+j
    f16x8 w0hi[2][4], w0lo[2][4], w1hi[2][4], w1lo[2][4];
    float bs0[2], bs1[2];
    #pragma unroll
    for (int t = 0; t < 2; ++t) {
        int n = w * 32 + t * 16 + m;
        bs0[t] = b0v[n];
        bs1[t] = b1v[n];
        const float* r0 = W0 + (size_t)n * 128 + q * 8;
        const float* r1 = W1 + (size_t)n * 128 + q * 8;
        #pragma unroll
        for (int kb = 0; kb < 4; ++kb) {
            float4 a0 = *(const float4*)(r0 + kb * 32);
            float4 a1 = *(const float4*)(r0 + kb * 32 + 4);
            float4 c0 = *(const float4*)(r1 + kb * 32);
            float4 c1 = *(const float4*)(r1 + kb * 32 + 4);
            float fa[8] = {a0.x,a0.y,a0.z,a0.w,a1.x,a1.y,a1.z,a1.w};
            float fc[8] = {c0.x,c0.y,c0.z,c0.w,c1.x,c1.y,c1.z,c1.w};
            f16x8 h0, l0, h1, l1;
            #pragma unroll
            for (int j = 0; j < 8; ++j) {
                _Float16 ha = (_Float16)fa[j];
                _Float16 hc = (_Float16)fc[j];
                h0[j] = ha; l0[j] = (_Float16)(fa[j] - (float)ha);
                h1[j] = hc; l1[j] = (_Float16)(fc[j] - (float)hc);
            }
            w0hi[t][kb] = h0; w0lo[t][kb] = l0;
            w1hi[t][kb] = h1; w1lo[t][kb] = l1;
        }
    }

    const float ep = 1.f + eps[layer];
    const u32* h32 = (const u32*)hin;
    const int rdrow = lane >> 2, rdcg = lane & 3;

    for (int tile = blockIdx.x; tile < NT; tile += gridDim.x) {
        int row0 = tile * 16;
        // ---- aggregation: wave w handles 4 nodes ----
        #pragma unroll
        for (int j = 0; j < 4; ++j) {
            int node = row0 + w * 4 + j;
            int e0 = rp[node], e1 = rp[node + 1];
            u32 sv = h32[(size_t)node * 64 + lane];
            float a0 = ep * h2f((u16)(sv & 0xffff));
            float a1 = ep * h2f((u16)(sv >> 16));
            int e = e0;
            if ((e & 1) && e < e1) {
                int2 pp = pairs[e];
                float wt = __int_as_float(pp.y);
                u32 v = h32[(size_t)pp.x * 64 + lane];
                a0 += wt * h2f((u16)(v & 0xffff));
                a1 += wt * h2f((u16)(v >> 16));
                ++e;
            }
            for (; e + 8 <= e1; e += 8) {
                int4 p0 = *(const int4*)(pairs + e);
                int4 p1 = *(const int4*)(pairs + e + 2);
                int4 p2 = *(const int4*)(pairs + e + 4);
                int4 p3 = *(const int4*)(pairs + e + 6);
                u32 v0 = h32[(size_t)p0.x * 64 + lane];
                u32 v1 = h32[(size_t)p0.z * 64 + lane];
                u32 v2 = h32[(size_t)p1.x * 64 + lane];
                u32 v3 = h32[(size_t)p1.z * 64 + lane];
                u32 v4 = h32[(size_t)p2.x * 64 + lane];
                u32 v5 = h32[(size_t)p2.z * 64 + lane];
                u32 v6 = h32[(size_t)p3.x * 64 + lane];
                u32 v7 = h32[(size_t)p3.z * 64 + lane];
                float w0 = __int_as_float(p0.y), w1 = __int_as_float(p0.w);
                float w2 = __int_as_float(p1.y), w3 = __int_as_float(p1.w);
                float w4 = __int_as_float(p2.y), w5 = __int_as_float(p2.w);
                float w6 = __int_as_float(p3.y), w7 = __int_as_float(p3.w);
                a0 += w0 * h2f((u16)(v0 & 0xffff)) + w1 * h2f((u16)(v1 & 0xffff))
                    + w2 * h2f((u16)(v2 & 0xffff)) + w3 * h2f((u16)(v3 & 0xffff))
                    + w4 * h2f((u16)(v4 & 0xffff)) + w5 * h2f((u16)(v5 & 0xffff))
                    + w6 * h2f((u16)(v6 & 0xffff)) + w7 * h2f((u16)(v7 & 0xffff));
                a1 += w0 * h2f((u16)(v0 >> 16)) + w1 * h2f((u16)(v1 >> 16))
                    + w2 * h2f((u16)(v2 >> 16)) + w3 * h2f((u16)(v3 >> 16))
                    + w4 * h2f((u16)(v4 >> 16)) + w5 * h2f((u16)(v5 >> 16))
                    + w6 * h2f((u16)(v6 >> 16)) + w7 * h2f((u16)(v7 >> 16));
            }
            for (; e + 2 <= e1; e += 2) {
                int4 p0 = *(const int4*)(pairs + e);
                float w0 = __int_as_float(p0.y), w1 = __int_as_float(p0.w);
                u32 v0 = h32[(size_t)p0.x * 64 + lane];
                u32 v1 = h32[(size_t)p0.z * 64 + lane];
                a0 += w0 * h2f((u16)(v0 & 0xffff)) + w1 * h2f((u16)(v1 & 0xffff));
                a1 += w0 * h2f((u16)(v0 >> 16)) + w1 * h2f((u16)(v1 >> 16));
            }
            if (e < e1) {
                int2 pp = pairs[e];
                float wt = __int_as_float(pp.y);
                u32 v = h32[(size_t)pp.x * 64 + lane];
                a0 += wt * h2f((u16)(v & 0xffff));
                a1 += wt * h2f((u16)(v >> 16));
            }
            *(u32*)&tA[(w * 4 + j) * 136 + lane * 2] =
                (u32)f2h(a0) | ((u32)f2h(a1) << 16);
        }
        __syncthreads();
        // ---- SLP0: A from tA, write relu result to tB ----
        f16x8 af[4];
        #pragma unroll
        for (int kb = 0; kb < 4; ++kb) {
            U16x8 u; u.u = *(const uint4*)&tA[m * 136 + kb * 32 + q * 8];
            af[kb] = u.h;
        }
        f32x4 acc[2] = {{0.f,0.f,0.f,0.f},{0.f,0.f,0.f,0.f}};
        #pragma unroll
        for (int t = 0; t < 2; ++t)
            #pragma unroll
            for (int kb = 0; kb < 4; ++kb) {
                acc[t] = __builtin_amdgcn_mfma_f32_16x16x32_f16(af[kb], w0hi[t][kb], acc[t], 0, 0, 0);
                acc[t] = __builtin_amdgcn_mfma_f32_16x16x32_f16(af[kb], w0lo[t][kb], acc[t], 0, 0, 0);
            }
        #pragma unroll
        for (int t = 0; t < 2; ++t)
            #pragma unroll
            for (int r = 0; r < 4; ++r) {
                float v = fmaxf(acc[t][r] + bs0[t], 0.f);
                tB[(q * 4 + r) * 136 + w * 32 + t * 16 + m] = f2h(v);
            }
        __syncthreads();
        // ---- SLP1: A from tB, epilogue ----
        #pragma unroll
        for (int kb = 0; kb < 4; ++kb) {
            U16x8 u; u.u = *(const uint4*)&tB[m * 136 + kb * 32 + q * 8];
            af[kb] = u.h;
        }
        f32x4 ac2[2] = {{0.f,0.f,0.f,0.f},{0.f,0.f,0.f,0.f}};
        #pragma unroll
        for (int t = 0; t < 2; ++t)
            #pragma unroll
            for (int kb = 0; kb < 4; ++kb) {
                ac2[t] = __builtin_amdgcn_mfma_f32_16x16x32_f16(af[kb], w1hi[t][kb], ac2[t], 0, 0, 0);
                ac2[t] = __builtin_amdgcn_mfma_f32_16x16x32_f16(af[kb], w1lo[t][kb], ac2[t], 0, 0, 0);
            }
        #pragma unroll
        for (int t = 0; t < 2; ++t)
            #pragma unroll
            for (int r = 0; r < 4; ++r)
                st[(q * 4 + r) * 36 + t * 16 + m] = fmaxf(ac2[t][r] + bs1[t], 0.f);
        float4 v0 = *(const float4*)&st[rdrow * 36 + rdcg * 8];
        float4 v1 = *(const float4*)&st[rdrow * 36 + rdcg * 8 + 4];
        size_t gbase = (size_t)(row0 + rdrow) * 128 + w * 32 + rdcg * 8;
        U16x8 p;
        p.s[0] = f2h(v0.x); p.s[1] = f2h(v0.y); p.s[2] = f2h(v0.z); p.s[3] = f2h(v0.w);
        p.s[4] = f2h(v1.x); p.s[5] = f2h(v1.y); p.s[6] = f2h(v1.z); p.s[7] = f2h(v1.w);
        *(uint4*)(outh + gbase) = p.u;
        *(float4*)(outf + gbase) = v0;
        *(float4*)(outf + gbase + 4) = v1;
        // no 3rd sync needed: tA rewrites happen after next-iter sync1; tB
        // rewrites happen after next sync1 too (every wave has finished its
        // SLP1 reads before reaching it).
    }
}

// ---------------- graph pooling from fp16 embeds ----------------
__device__ __forceinline__ int lbound(const int* b, int n, int v) {
    int lo = 0, hi = n;
    while (lo < hi) { int mid = (lo + hi) >> 1; if (b[mid] < v) lo = mid + 1; else hi = mid; }
    return lo;
}

__global__ __launch_bounds__(128) void k_pool_partial(const u16* __restrict__ embH,
                                                      const int* __restrict__ batch,
                                                      float* __restrict__ ps_tmp) {
    int g = blockIdx.x >> 3, s = blockIdx.x & 7, t = threadIdx.x;
    int lo = lbound(batch, NN, g);
    int hi = lbound(batch, NN, g + 1);
    float acc = 0.f;
    for (int n = lo + s; n < hi; n += 8) {
        size_t base = (size_t)n * 128 + t;
        #pragma unroll
        for (int e = 0; e < 5; ++e)
            acc += h2f(embH[(size_t)e * NN * 128 + base]);
    }
    atomicAdd(&ps_tmp[g * 128 + t], acc);
}

// ---------------- head ----------------
__global__ __launch_bounds__(128) void k_final(const float* __restrict__ ps_tmp,
                                               const float* __restrict__ W1, const float* __restrict__ b1,
                                               const float* __restrict__ W2, const float* __restrict__ b2,
                                               float* __restrict__ out) {
    int g = blockIdx.x, t = threadIdx.x;
    __shared__ float ps[128], l1[128], l2[8];
    float v = ps_tmp[g * 128 + t];
    ps[t] = v;
    out[OFF_PS + (size_t)g * 128 + t] = v;
    __syncthreads();
    float a = b1[t];
    #pragma unroll 8
    for (int k = 0; k < 128; ++k) a += ps[k] * W1[t * 128 + k];
    a = fmaxf(a, 0.f);
    l1[t] = a;
    out[OFF_L1  + (size_t)g * 128 + t] = a;
    out[OFF_L1D + (size_t)g * 128 + t] = a;
    __syncthreads();
    if (t < 8) {
        float a2 = b2[t];
        #pragma unroll 8
        for (int k = 0; k < 128; ++k) a2 += l1[k] * W2[t * 128 + k];
        l2[t] = a2;
        out[OFF_L2 + (size_t)g * 8 + t] = a2;
    }
    __syncthreads();
    if (t == 0) {
        float mx = l2[0];
        for (int j = 1; j < 8; ++j) mx = fmaxf(mx, l2[j]);
        float e[8], s = 0.f;
        for (int j = 0; j < 8; ++j) { e[j] = __expf(l2[j] - mx); s += e[j]; }
        float inv = 1.f / s;
        for (int j = 0; j < 8; ++j) out[OFF_SOFT + (size_t)g * 8 + j] = e[j] * inv;
    }
}

extern "C" void kernel_launch(void* const* d_in, const int* in_sizes, int n_in,
                              void* d_out, int out_size, void* d_ws, size_t ws_size,
                              hipStream_t stream) {
    const float* x       = (const float*)d_in[0];
    const int*   ei      = (const int*)d_in[1];
    const float* emask   = (const float*)d_in[2];
    const int*   batch   = (const int*)d_in[3];
    const float* eps     = (const float*)d_in[4];
    const float* W_first = (const float*)d_in[5];
    const float* b_first = (const float*)d_in[6];
    const float* gin_W   = (const float*)d_in[7];
    const float* gin_b   = (const float*)d_in[8];
    const float* W1      = (const float*)d_in[9];
    const float* b1      = (const float*)d_in[10];
    const float* W2      = (const float*)d_in[11];
    const float* b2      = (const float*)d_in[12];
    float* out = (float*)d_out;

    char* ws = (char*)d_ws;
    const size_t HB = (size_t)NN * 128 * 2;       // 25.6 MB per fp16 node buffer
    u16* embH = (u16*)(ws);                       // 5 contiguous embed planes
    size_t o = 5 * HB;
    int2* pairs = (int2*)(ws + o); o += (size_t)NE * 8;
    int* cnt  = (int*)(ws + o); o += 400000;
    int* cur  = (int*)(ws + o); o += 400000;
    float* ps_tmp = (float*)(ws + o); o += (size_t)NG * DH * 4;
    int* rp   = (int*)(ws + o); o += 400064;
    int* bsum = (int*)(ws + o); o += 512;

    // one memset covers cnt + cur + ps_tmp (adjacent)
    hipMemsetAsync(cnt, 0, 400000 + 400000 + (size_t)NG * DH * 4, stream);

    // CSR build
    k_hist<<<NE / 256, 256, 0, stream>>>(ei, cnt);
    k_scan1<<<98, 256, 0, stream>>>(cnt, rp, bsum);
    k_scan2<<<1, 128, 0, stream>>>(bsum, 98);
    k_scan3<<<98, 256, 0, stream>>>(rp, bsum);
    k_scatter<<<NE / 256, 256, 0, stream>>>(ei, emask, rp, cur, pairs);

    // first linear: x -> embH[0] (+ fp32 embeds[0])
    k_gemm0<<<1024, 256, 0, stream>>>(x, W_first, b_first, embH, out + OFF_EMB);

    // fused GIN layers
    for (int l = 0; l < NL; ++l) {
        k_layer<<<512, 256, 0, stream>>>(
            embH + (size_t)l * NN * 128, pairs, rp, eps, l,
            gin_W + (size_t)(l * 2 + 0) * 128 * 128, gin_b + (size_t)(l * 2 + 0) * 128,
            gin_W + (size_t)(l * 2 + 1) * 128 * 128, gin_b + (size_t)(l * 2 + 1) * 128,
            embH + (size_t)(l + 1) * NN * 128,
            out + OFF_EMB + (size_t)(l + 1) * NN * 128);
    }

    k_pool_partial<<<NG * 8, 128, 0, stream>>>(embH, batch, ps_tmp);
    k_final<<<NG, 128, 0, stream>>>(ps_tmp, W1, b1, W2, b2, out);
}